// Round 1
// baseline (1544.133 us; speedup 1.0000x reference)
//
#include <hip/hip_runtime.h>
#include <stdint.h>

#define RADIX 256
#define TILE 1024          // keys per block per radix pass (64-thread blocks, 16 chunks)

// ---------------- hashing ----------------
__device__ __forceinline__ uint32_t hash4(int4 v) {
    // ((b*1025 + z)*1025 + y)*1025 + x  — fits in uint32 (max 3,273,746,473)
    uint32_t h = (uint32_t)v.x * 1025u + (uint32_t)v.y;
    h = h * 1025u + (uint32_t)v.z;
    h = h * 1025u + (uint32_t)v.w;
    return h;
}

__global__ void hash_students(const int* __restrict__ sidx, uint32_t* __restrict__ keys, int ns) {
    int i = blockIdx.x * blockDim.x + threadIdx.x;
    if (i >= ns) return;
    keys[i] = hash4(((const int4*)sidx)[i]);
}

// ---------------- radix sort: histogram ----------------
__global__ void radix_hist(const uint32_t* __restrict__ keys, uint32_t* __restrict__ hist,
                           int ns, int nblk, int shift) {
    __shared__ uint32_t cnt[RADIX];
    for (int d = threadIdx.x; d < RADIX; d += 64) cnt[d] = 0;
    __syncthreads();
    int base = blockIdx.x * TILE;
    for (int c = 0; c < TILE; c += 64) {
        int i = base + c + (int)threadIdx.x;
        if (i < ns) {
            uint32_t d = (keys[i] >> shift) & 255u;
            atomicAdd(&cnt[d], 1u);
        }
    }
    __syncthreads();
    for (int d = threadIdx.x; d < RADIX; d += 64)
        hist[(size_t)d * nblk + blockIdx.x] = cnt[d];
}

// ---------------- scan helpers ----------------
__device__ __forceinline__ uint32_t block_incl_scan_256(uint32_t v, uint32_t* s) {
    int t = threadIdx.x;
    s[t] = v;
    __syncthreads();
    #pragma unroll
    for (int off = 1; off < 256; off <<= 1) {
        uint32_t u = (t >= off) ? s[t - off] : 0u;
        __syncthreads();
        s[t] += u;
        __syncthreads();
    }
    return s[t];
}

// one block per digit: exclusive scan across blocks within the digit
__global__ void radix_scanA(uint32_t* __restrict__ hist, uint32_t* __restrict__ dtot, int nblk) {
    __shared__ uint32_t s[256];
    int d = blockIdx.x;
    uint32_t run = 0;
    for (int c = 0; c < nblk; c += 256) {
        int i = c + (int)threadIdx.x;
        uint32_t v = (i < nblk) ? hist[(size_t)d * nblk + i] : 0u;
        uint32_t incl = block_incl_scan_256(v, s);
        if (i < nblk) hist[(size_t)d * nblk + i] = incl - v + run;
        run += s[255];
        __syncthreads();
    }
    if (threadIdx.x == 0) dtot[d] = run;
}

// single block: exclusive scan of the 256 digit totals
__global__ void radix_scanB(uint32_t* __restrict__ dtot) {
    __shared__ uint32_t s[256];
    uint32_t v = dtot[threadIdx.x];
    uint32_t incl = block_incl_scan_256(v, s);
    dtot[threadIdx.x] = incl - v;
}

// add digit base to every per-block offset
__global__ void radix_scanC(uint32_t* __restrict__ hist, const uint32_t* __restrict__ dtot, int nblk) {
    int d = blockIdx.x;
    uint32_t base = dtot[d];
    for (int i = threadIdx.x; i < nblk; i += blockDim.x)
        hist[(size_t)d * nblk + i] += base;
}

// ---------------- radix sort: stable scatter (1 wave per block) ----------------
__global__ void radix_scatter(const uint32_t* __restrict__ in, uint32_t* __restrict__ out,
                              const uint32_t* __restrict__ hist, int ns, int nblk, int shift) {
    __shared__ uint32_t nxt[RADIX];
    int b = blockIdx.x;
    for (int d = threadIdx.x; d < RADIX; d += 64)
        nxt[d] = hist[(size_t)d * nblk + b];
    __syncthreads();

    int lane = threadIdx.x;                       // 64 threads == 1 wave
    uint64_t lanemask_lt = (lane == 0) ? 0ull : ((1ull << lane) - 1ull);
    int base = b * TILE;
    for (int c = 0; c < TILE; c += 64) {
        int i = base + c + lane;
        bool valid = (i < ns);
        uint32_t key = valid ? in[i] : 0u;
        uint32_t dg = (key >> shift) & 255u;
        // group lanes with identical digit via 8 ballots
        uint64_t mask = __ballot(valid);
        #pragma unroll
        for (int k = 0; k < 8; ++k) {
            uint64_t bb = __ballot(valid && ((dg >> k) & 1u));
            mask &= ((dg >> k) & 1u) ? bb : ~bb;
        }
        if (valid) {
            int leader = (int)__builtin_ctzll(mask);
            uint32_t rank = (uint32_t)__builtin_popcountll(mask & lanemask_lt);
            uint32_t basev = nxt[dg];             // same-address LDS read -> broadcast
            out[basev + rank] = key;
            if (lane == leader)
                nxt[dg] = basev + (uint32_t)__builtin_popcountll(mask);
        }
        __syncthreads();                          // order LDS update before next chunk
    }
}

// ---------------- outputs ----------------
// indice: decode sorted hash -> (b,z,y,x), write as float32 (exact for <=1024)
__global__ void write_indice(const uint32_t* __restrict__ keys, float* __restrict__ outI, int ns) {
    int i = blockIdx.x * blockDim.x + threadIdx.x;
    if (i >= ns) return;
    uint32_t h = keys[i];
    uint32_t x = h % 1025u; h /= 1025u;
    uint32_t y = h % 1025u; h /= 1025u;
    uint32_t z = h % 1025u;
    uint32_t bb = h / 1025u;
    ((float4*)outI)[i] = make_float4((float)bb, (float)z, (float)y, (float)x);
}

// teacher pass: hash, binary-search sorted student keys, accumulate features
__global__ void teacher_scatter(const int* __restrict__ tidx, const float* __restrict__ tfeat,
                                const uint32_t* __restrict__ keys, float* __restrict__ feat,
                                int nt, int ns, int C) {
    int t = blockIdx.x * blockDim.x + threadIdx.x;
    if (t >= nt) return;
    uint32_t h = hash4(((const int4*)tidx)[t]);
    int lo = 0, hi = ns;
    while (lo < hi) {
        int mid = (lo + hi) >> 1;
        if (keys[mid] < h) lo = mid + 1; else hi = mid;
    }
    if (lo < ns && keys[lo] == h) {
        const float4* src = (const float4*)(tfeat + (size_t)t * C);
        float* dst = feat + (size_t)lo * C;
        #pragma unroll
        for (int q = 0; q < 8; ++q) {            // C == 32
            float4 f = src[q];
            atomicAdd(dst + q * 4 + 0, f.x);
            atomicAdd(dst + q * 4 + 1, f.y);
            atomicAdd(dst + q * 4 + 2, f.z);
            atomicAdd(dst + q * 4 + 3, f.w);
        }
    }
}

extern "C" void kernel_launch(void* const* d_in, const int* in_sizes, int n_in,
                              void* d_out, int out_size, void* d_ws, size_t ws_size,
                              hipStream_t stream) {
    const float* tfeat = (const float*)d_in[0];
    const int*   tidx  = (const int*)d_in[1];
    const int*   sidx  = (const int*)d_in[2];

    const int NT = in_sizes[1] / 4;
    const int NS = in_sizes[2] / 4;
    const int C  = in_sizes[0] / NT;   // 32

    float* feat = (float*)d_out;                        // [NS, C]
    float* outI = (float*)d_out + (size_t)NS * C;       // [NS, 4] as floats

    // workspace layout (uint32)
    uint32_t* ws32  = (uint32_t*)d_ws;
    uint32_t* keysA = ws32;
    uint32_t* keysB = ws32 + NS;
    const int NBLK  = (NS + TILE - 1) / TILE;
    uint32_t* hist  = ws32 + 2 * (size_t)NS;
    uint32_t* dtot  = hist + (size_t)RADIX * NBLK;

    // zero the accumulated feat region every call (atomics accumulate)
    hipMemsetAsync(d_out, 0, (size_t)NS * C * sizeof(float), stream);

    hash_students<<<(NS + 255) / 256, 256, 0, stream>>>(sidx, keysA, NS);

    uint32_t* cur = keysA;
    uint32_t* oth = keysB;
    for (int pass = 0; pass < 4; ++pass) {
        int shift = pass * 8;
        radix_hist<<<NBLK, 64, 0, stream>>>(cur, hist, NS, NBLK, shift);
        radix_scanA<<<RADIX, 256, 0, stream>>>(hist, dtot, NBLK);
        radix_scanB<<<1, 256, 0, stream>>>(dtot);
        radix_scanC<<<RADIX, 256, 0, stream>>>(hist, dtot, NBLK);
        radix_scatter<<<NBLK, 64, 0, stream>>>(cur, oth, hist, NS, NBLK, shift);
        uint32_t* tmp = cur; cur = oth; oth = tmp;
    }
    // 4 passes -> sorted keys back in keysA (== cur)

    write_indice<<<(NS + 255) / 256, 256, 0, stream>>>(cur, outI, NS);
    teacher_scatter<<<(NT + 255) / 256, 256, 0, stream>>>(tidx, tfeat, cur, feat, NT, NS, C);
}

// Round 2
// 1534.457 us; speedup vs baseline: 1.0063x; 1.0063x over previous
//
#include <hip/hip_runtime.h>
#include <stdint.h>

#define RADIX 256
#define TILE 1024          // keys per block per radix pass (64-thread blocks, 16 chunks)

// ---------------- hashing ----------------
__device__ __forceinline__ uint32_t hash4(int4 v) {
    // ((b*1025 + z)*1025 + y)*1025 + x  — fits in uint32 (max 3,273,746,473)
    uint32_t h = (uint32_t)v.x * 1025u + (uint32_t)v.y;
    h = h * 1025u + (uint32_t)v.z;
    h = h * 1025u + (uint32_t)v.w;
    return h;
}

__global__ void hash_students(const int* __restrict__ sidx, uint32_t* __restrict__ keys, int ns) {
    int i = blockIdx.x * blockDim.x + threadIdx.x;
    if (i >= ns) return;
    keys[i] = hash4(((const int4*)sidx)[i]);
}

// ---------------- radix sort: histogram ----------------
__global__ void radix_hist(const uint32_t* __restrict__ keys, uint32_t* __restrict__ hist,
                           int ns, int nblk, int shift) {
    __shared__ uint32_t cnt[RADIX];
    for (int d = threadIdx.x; d < RADIX; d += 64) cnt[d] = 0;
    __syncthreads();
    int base = blockIdx.x * TILE;
    for (int c = 0; c < TILE; c += 64) {
        int i = base + c + (int)threadIdx.x;
        if (i < ns) {
            uint32_t d = (keys[i] >> shift) & 255u;
            atomicAdd(&cnt[d], 1u);
        }
    }
    __syncthreads();
    for (int d = threadIdx.x; d < RADIX; d += 64)
        hist[(size_t)d * nblk + blockIdx.x] = cnt[d];
}

// ---------------- scan helpers ----------------
__device__ __forceinline__ uint32_t block_incl_scan_256(uint32_t v, uint32_t* s) {
    int t = threadIdx.x;
    s[t] = v;
    __syncthreads();
    #pragma unroll
    for (int off = 1; off < 256; off <<= 1) {
        uint32_t u = (t >= off) ? s[t - off] : 0u;
        __syncthreads();
        s[t] += u;
        __syncthreads();
    }
    return s[t];
}

// one block per digit: exclusive scan across blocks within the digit
__global__ void radix_scanA(uint32_t* __restrict__ hist, uint32_t* __restrict__ dtot, int nblk) {
    __shared__ uint32_t s[256];
    int d = blockIdx.x;
    uint32_t run = 0;
    for (int c = 0; c < nblk; c += 256) {
        int i = c + (int)threadIdx.x;
        uint32_t v = (i < nblk) ? hist[(size_t)d * nblk + i] : 0u;
        uint32_t incl = block_incl_scan_256(v, s);
        if (i < nblk) hist[(size_t)d * nblk + i] = incl - v + run;
        run += s[255];
        __syncthreads();
    }
    if (threadIdx.x == 0) dtot[d] = run;
}

// single block: exclusive scan of the 256 digit totals
__global__ void radix_scanB(uint32_t* __restrict__ dtot) {
    __shared__ uint32_t s[256];
    uint32_t v = dtot[threadIdx.x];
    uint32_t incl = block_incl_scan_256(v, s);
    dtot[threadIdx.x] = incl - v;
}

// add digit base to every per-block offset
__global__ void radix_scanC(uint32_t* __restrict__ hist, const uint32_t* __restrict__ dtot, int nblk) {
    int d = blockIdx.x;
    uint32_t base = dtot[d];
    for (int i = threadIdx.x; i < nblk; i += blockDim.x)
        hist[(size_t)d * nblk + i] += base;
}

// ---------------- radix sort: stable scatter (1 wave per block) ----------------
__global__ void radix_scatter(const uint32_t* __restrict__ in, uint32_t* __restrict__ out,
                              const uint32_t* __restrict__ hist, int ns, int nblk, int shift) {
    __shared__ uint32_t nxt[RADIX];
    int b = blockIdx.x;
    for (int d = threadIdx.x; d < RADIX; d += 64)
        nxt[d] = hist[(size_t)d * nblk + b];
    __syncthreads();

    int lane = threadIdx.x;                       // 64 threads == 1 wave
    uint64_t lanemask_lt = (lane == 0) ? 0ull : ((1ull << lane) - 1ull);
    int base = b * TILE;
    for (int c = 0; c < TILE; c += 64) {
        int i = base + c + lane;
        bool valid = (i < ns);
        uint32_t key = valid ? in[i] : 0u;
        uint32_t dg = (key >> shift) & 255u;
        // group lanes with identical digit via 8 ballots
        uint64_t mask = __ballot(valid);
        #pragma unroll
        for (int k = 0; k < 8; ++k) {
            uint64_t bb = __ballot(valid && ((dg >> k) & 1u));
            mask &= ((dg >> k) & 1u) ? bb : ~bb;
        }
        if (valid) {
            int leader = (int)__builtin_ctzll(mask);
            uint32_t rank = (uint32_t)__builtin_popcountll(mask & lanemask_lt);
            uint32_t basev = nxt[dg];             // same-address LDS read -> broadcast
            out[basev + rank] = key;
            if (lane == leader)
                nxt[dg] = basev + (uint32_t)__builtin_popcountll(mask);
        }
        __syncthreads();                          // order LDS update before next chunk
    }
}

// ---------------- outputs ----------------
// indice: decode sorted hash -> (b,z,y,x), write as float32 (exact for <=1024)
__global__ void write_indice(const uint32_t* __restrict__ keys, float* __restrict__ outI, int ns) {
    int i = blockIdx.x * blockDim.x + threadIdx.x;
    if (i >= ns) return;
    uint32_t h = keys[i];
    uint32_t x = h % 1025u; h /= 1025u;
    uint32_t y = h % 1025u; h /= 1025u;
    uint32_t z = h % 1025u;
    uint32_t bb = h / 1025u;
    ((float4*)outI)[i] = make_float4((float)bb, (float)z, (float)y, (float)x);
}

// teacher pass: hash, binary-search sorted student keys, accumulate features
__global__ void teacher_scatter(const int* __restrict__ tidx, const float* __restrict__ tfeat,
                                const uint32_t* __restrict__ keys, float* __restrict__ feat,
                                int nt, int ns, int C) {
    int t = blockIdx.x * blockDim.x + threadIdx.x;
    if (t >= nt) return;
    uint32_t h = hash4(((const int4*)tidx)[t]);
    int lo = 0, hi = ns;
    while (lo < hi) {
        int mid = (lo + hi) >> 1;
        if (keys[mid] < h) lo = mid + 1; else hi = mid;
    }
    if (lo < ns && keys[lo] == h) {
        const float4* src = (const float4*)(tfeat + (size_t)t * C);
        float* dst = feat + (size_t)lo * C;
        #pragma unroll
        for (int q = 0; q < 8; ++q) {            // C == 32
            float4 f = src[q];
            atomicAdd(dst + q * 4 + 0, f.x);
            atomicAdd(dst + q * 4 + 1, f.y);
            atomicAdd(dst + q * 4 + 2, f.z);
            atomicAdd(dst + q * 4 + 3, f.w);
        }
    }
}

extern "C" void kernel_launch(void* const* d_in, const int* in_sizes, int n_in,
                              void* d_out, int out_size, void* d_ws, size_t ws_size,
                              hipStream_t stream) {
    const float* tfeat = (const float*)d_in[0];
    const int*   tidx  = (const int*)d_in[1];
    const int*   sidx  = (const int*)d_in[2];

    const int NT = in_sizes[1] / 4;
    const int NS = in_sizes[2] / 4;
    const int C  = in_sizes[0] / NT;   // 32

    float* feat = (float*)d_out;                        // [NS, C]
    float* outI = (float*)d_out + (size_t)NS * C;       // [NS, 4] as floats

    // workspace layout (uint32)
    uint32_t* ws32  = (uint32_t*)d_ws;
    uint32_t* keysA = ws32;
    uint32_t* keysB = ws32 + NS;
    const int NBLK  = (NS + TILE - 1) / TILE;
    uint32_t* hist  = ws32 + 2 * (size_t)NS;
    uint32_t* dtot  = hist + (size_t)RADIX * NBLK;

    // zero the accumulated feat region every call (atomics accumulate)
    hipMemsetAsync(d_out, 0, (size_t)NS * C * sizeof(float), stream);

    hash_students<<<(NS + 255) / 256, 256, 0, stream>>>(sidx, keysA, NS);

    uint32_t* cur = keysA;
    uint32_t* oth = keysB;
    for (int pass = 0; pass < 4; ++pass) {
        int shift = pass * 8;
        radix_hist<<<NBLK, 64, 0, stream>>>(cur, hist, NS, NBLK, shift);
        radix_scanA<<<RADIX, 256, 0, stream>>>(hist, dtot, NBLK);
        radix_scanB<<<1, 256, 0, stream>>>(dtot);
        radix_scanC<<<RADIX, 256, 0, stream>>>(hist, dtot, NBLK);
        radix_scatter<<<NBLK, 64, 0, stream>>>(cur, oth, hist, NS, NBLK, shift);
        uint32_t* tmp = cur; cur = oth; oth = tmp;
    }
    // 4 passes -> sorted keys back in keysA (== cur)

    write_indice<<<(NS + 255) / 256, 256, 0, stream>>>(cur, outI, NS);
    teacher_scatter<<<(NT + 255) / 256, 256, 0, stream>>>(tidx, tfeat, cur, feat, NT, NS, C);
}